// Round 1
// baseline (21.066 us; speedup 1.0000x reference)
//
#include <hip/hip_runtime.h>

// Exact reference semantics: (sign(t-0.5)+1)*0.5  -> {0, 0.5, 1}
__device__ __forceinline__ float binarize(float t) {
    float d = t - 0.5f;
    float s = (d > 0.0f) ? 1.0f : ((d < 0.0f) ? -1.0f : 0.0f);
    return (s + 1.0f) * 0.5f;
}

__global__ __launch_bounds__(256) void Packetbnn_kernel(
    const float* __restrict__ x,       // [B, 5] flattened
    const float* __restrict__ w_conv,  // [5, 5] flattened (OIHW with I=H=1)
    const float* __restrict__ w_lin,   // [5]
    float* __restrict__ out,           // [B]
    int nquad,                         // number of 4-row quads
    int nrows)                         // B
{
    // Binarized weights — uniform addresses, L1/L2 resident, hoisted to regs.
    float wcb[5][5];
#pragma unroll
    for (int o = 0; o < 5; ++o)
#pragma unroll
        for (int k = 0; k < 5; ++k)
            wcb[o][k] = binarize(w_conv[o * 5 + k]);
    float wlb[5];
#pragma unroll
    for (int o = 0; o < 5; ++o) wlb[o] = binarize(w_lin[o]);

    int t = blockIdx.x * blockDim.x + threadIdx.x;
    if (t >= nquad) return;

    // 4 rows = 20 floats = 5 coalesced float4 loads per thread.
    const float4* xv = reinterpret_cast<const float4*>(x) + (size_t)t * 5;
    float4 v0 = xv[0], v1 = xv[1], v2 = xv[2], v3 = xv[3], v4 = xv[4];
    float r[20] = {v0.x, v0.y, v0.z, v0.w,
                   v1.x, v1.y, v1.z, v1.w,
                   v2.x, v2.y, v2.z, v2.w,
                   v3.x, v3.y, v3.z, v3.w,
                   v4.x, v4.y, v4.z, v4.w};

    float res[4];
#pragma unroll
    for (int q = 0; q < 4; ++q) {
        float xb[5];
#pragma unroll
        for (int k = 0; k < 5; ++k) xb[k] = binarize(r[q * 5 + k]);
        float acc = 0.0f;
#pragma unroll
        for (int o = 0; o < 5; ++o) {
            float c = 0.0f;
#pragma unroll
            for (int k = 0; k < 5; ++k) c += xb[k] * wcb[o][k];
            acc += binarize(c) * wlb[o];
        }
        res[q] = acc;
    }

    float4 o4 = {res[0], res[1], res[2], res[3]};
    reinterpret_cast<float4*>(out)[t] = o4;

    // Tail rows (nrows not divisible by 4) — handled by thread 0 (B=4194304
    // is divisible by 4, so this is normally dead code, kept for safety).
    if (t == 0) {
        for (int row = nquad * 4; row < nrows; ++row) {
            float xb[5];
            for (int k = 0; k < 5; ++k) xb[k] = binarize(x[(size_t)row * 5 + k]);
            float acc = 0.0f;
            for (int o = 0; o < 5; ++o) {
                float c = 0.0f;
                for (int k = 0; k < 5; ++k) c += xb[k] * wcb[o][k];
                acc += binarize(c) * wlb[o];
            }
            out[row] = acc;
        }
    }
}

extern "C" void kernel_launch(void* const* d_in, const int* in_sizes, int n_in,
                              void* d_out, int out_size, void* d_ws, size_t ws_size,
                              hipStream_t stream) {
    const float* x      = (const float*)d_in[0];  // [B,1,1,5]
    const float* w_conv = (const float*)d_in[1];  // [5,1,1,5]
    const float* w_lin  = (const float*)d_in[2];  // [1,5]
    float* out = (float*)d_out;                   // [B,1]

    int nrows = out_size;          // B
    int nquad = nrows / 4;
    int threads = 256;
    int blocks = (nquad + threads - 1) / threads;
    if (blocks < 1) blocks = 1;

    Packetbnn_kernel<<<blocks, threads, 0, stream>>>(x, w_conv, w_lin, out,
                                                     nquad, nrows);
}